// Round 16
// baseline (76.622 us; speedup 1.0000x reference)
//
#include <hip/hip_runtime.h>

typedef unsigned short ushort_t;
typedef __attribute__((ext_vector_type(8))) short bfrag;
typedef __attribute__((ext_vector_type(4))) float f4;

// B=4, D=256, H=W=64, num_levels=4, radius=4
#define NB 4
#define ND 256
#define NH 64
#define NW 64
#define NQ (NH * NW)            // 4096 queries per batch
#define MPAD 5504               // 43 * 128 rows of pooled-f2 features
#define NLVL 4
#define NCH (NLVL * 81)

__device__ __forceinline__ float bf2f(ushort_t u) {
    return __uint_as_float(((unsigned)u) << 16);
}
__device__ __forceinline__ ushort_t f2bf(float f) {
    unsigned u = __float_as_uint(f);
    unsigned r = (u + 0x7fffu + ((u >> 16) & 1u)) >> 16;
    return (ushort_t)r;
}

__device__ __forceinline__ void gload_lds16(const void* g, void* l) {
    __builtin_amdgcn_global_load_lds(
        (const __attribute__((address_space(1))) unsigned int*)g,
        (__attribute__((address_space(3))) unsigned int*)l, 16, 0, 0);
}

// ---------- kernel 0: counting sort by y0 -> perm + sorted level tables ----------
// one block per batch; 256 threads, 16 queries each
__global__ __launch_bounds__(256) void sort_kernel(
    const float* __restrict__ coords,
    int* __restrict__ perm,             // [NB][4096] sorted pos -> true q
    int* __restrict__ tblS)             // [NB][4][4096] x0 | y0<<6 | q<<12 (sorted)
{
    __shared__ int hist[64];
    __shared__ int base[64];
    const int tid = threadIdx.x;
    const int b   = blockIdx.x;
    if (tid < 64) hist[tid] = 0;
    __syncthreads();
    int   keys[16];
    float cxs[16], cys[16];
#pragma unroll
    for (int i = 0; i < 16; i++) {
        int q = tid + i * 256;
        cxs[i] = coords[((size_t)b * 2 + 0) * NQ + q];
        cys[i] = coords[((size_t)b * 2 + 1) * NQ + q];
        keys[i] = (int)floorf(cys[i]);
        atomicAdd(&hist[keys[i]], 1);
    }
    __syncthreads();
    if (tid < 64) {                     // wave-parallel exclusive scan over 64 bins
        int v = hist[tid];
        int s = v;
#pragma unroll
        for (int off = 1; off < 64; off <<= 1) {
            int o = __shfl_up(s, off);
            if (tid >= off) s += o;
        }
        base[tid] = s - v;
    }
    __syncthreads();
#pragma unroll
    for (int i = 0; i < 16; i++) {
        int q = tid + i * 256;
        int pos = atomicAdd(&base[keys[i]], 1);
        perm[(size_t)b * NQ + pos] = q;
#pragma unroll
        for (int lvl = 0; lvl < 4; lvl++) {
            float s = 1.0f / (float)(1 << lvl);
            int x0 = (int)floorf(cxs[i] * s);
            int y0 = (int)floorf(cys[i] * s);
            tblS[(((size_t)b * 4 + lvl) << 12) + pos] = x0 | (y0 << 6) | (q << 12);
        }
    }
}

// ---------- kernel 1: fused transposes (linear writes) ----------
// z 0..3: fmap1 -> Abf (scaled 1/16); z 4..7: fmap2 -> Ball
__global__ __launch_bounds__(256) void pre_kernel(
    const float* __restrict__ f1, const float* __restrict__ f2,
    ushort_t* __restrict__ Abf, ushort_t* __restrict__ Ball)
{
    __shared__ float tile[64][65];
    const int tid = threadIdx.x;
    const int z = blockIdx.z;
    const int b = z & 3;
    const bool isA = (z < 4);
    const float* ib = (isA ? f1 : f2) + (size_t)b * ND * NQ;
    ushort_t* ob = isA ? (Abf + (size_t)b * NQ * ND) : (Ball + (size_t)b * MPAD * ND);
    const float scale = isA ? 0.0625f : 1.0f;
    const int n0 = blockIdx.x * 64, d0 = blockIdx.y * 64;
    const int nl = tid & 63, dg = tid >> 6;
#pragma unroll
    for (int i = 0; i < 16; i++) {
        int dl = dg + i * 4;
        tile[dl][nl] = ib[(size_t)(d0 + dl) * NQ + n0 + nl];
    }
    __syncthreads();
    const int dl = tid & 63, ng = tid >> 6;
#pragma unroll
    for (int i = 0; i < 16; i++) {
        int nn = ng + i * 4;
        ob[(size_t)(n0 + nn) * ND + d0 + dl] = f2bf(tile[dl][nn] * scale);
    }
}

// ---------- kernel 2: all 3 pyramid levels in one pass ----------
__global__ __launch_bounds__(256) void pool_fused(ushort_t* __restrict__ Ball)
{
    const int d = threadIdx.x;
    const int bid = blockIdx.x;          // 0 .. NB*64-1
    const int b = bid >> 6;
    const int cell = bid & 63;
    const int Y = cell >> 3, X = cell & 7;
    ushort_t* base = Ball + (size_t)b * MPAD * ND;

    float s1[4][4];
#pragma unroll
    for (int iy = 0; iy < 4; iy++)
#pragma unroll
        for (int ix = 0; ix < 4; ix++) {
            int ry = 2 * (4 * Y + iy), rx = 2 * (4 * X + ix);
            float s = bf2f(base[(size_t)((ry    ) * 64 + rx    ) * ND + d])
                    + bf2f(base[(size_t)((ry    ) * 64 + rx + 1) * ND + d])
                    + bf2f(base[(size_t)((ry + 1) * 64 + rx    ) * ND + d])
                    + bf2f(base[(size_t)((ry + 1) * 64 + rx + 1) * ND + d]);
            s1[iy][ix] = s * 0.25f;
            base[(size_t)(4096 + (4 * Y + iy) * 32 + 4 * X + ix) * ND + d] = f2bf(s1[iy][ix]);
        }
    float s2[2][2];
#pragma unroll
    for (int iy = 0; iy < 2; iy++)
#pragma unroll
        for (int ix = 0; ix < 2; ix++) {
            float s = 0.25f * (s1[2*iy][2*ix] + s1[2*iy][2*ix+1]
                             + s1[2*iy+1][2*ix] + s1[2*iy+1][2*ix+1]);
            s2[iy][ix] = s;
            base[(size_t)(5120 + (2 * Y + iy) * 16 + 2 * X + ix) * ND + d] = f2bf(s);
        }
    float s3 = 0.25f * (s2[0][0] + s2[0][1] + s2[1][0] + s2[1][1]);
    base[(size_t)(5376 + Y * 8 + X) * ND + d] = f2bf(s3);
}

// ---------- kernel 3: R13 GEMM (A gathered via perm) + sorted-query early exit ----------
// grid.x = 2752 = 4 batches * 16 M-tiles * 43 col-tiles, XCD-swizzled
__global__ __launch_bounds__(512, 4) void gemm_corr(
    const ushort_t* __restrict__ A,     // [NB][4096][256] bf16 (pre-scaled by 1/16)
    const ushort_t* __restrict__ Bm,    // [NB][MPAD][256] bf16
    ushort_t* __restrict__ compact,     // [NB][4096][400] bf16
    const int* __restrict__ perm,       // [NB][4096] sorted pos -> true q
    const int* __restrict__ tblS)       // [NB][4][4096] x0 | y0<<6 | q<<12 (sorted)
{
    __shared__ ushort_t As[3][256 * 32];    // 48 KiB
    __shared__ ushort_t Bs[3][128 * 32];    // 24 KiB

    // bijective XCD-chunk swizzle: 2752 = 8 * 344
    const int l   = blockIdx.x;
    const int wg  = (l & 7) * 344 + (l >> 3);
    const int z   = wg / 688;
    const int rem = wg - z * 688;
    const int by  = rem / 43;               // 0..15 (256-row M tiles)
    const int bxt = rem - by * 43;          // 0..42 (128-col tiles)

    int lvl, mbase;
    if (bxt < 32)      { lvl = 0; mbase = bxt * 128; }
    else if (bxt < 40) { lvl = 1; mbase = 4096 + (bxt - 32) * 128; }
    else if (bxt < 42) { lvl = 2; mbase = 5120 + (bxt - 40) * 128; }
    else               { lvl = 3; mbase = 5376; }

    const int* tbL = tblS + (((size_t)z * 4 + lvl) << 12);   // this level, sorted

    // ---- early exit: do my y-rows intersect any query's 10-wide window? ----
    if (lvl < 3) {
        int yF = (tbL[by * 256] >> 6) & 63;          // min y0 in tile (sorted)
        int yL = (tbL[by * 256 + 255] >> 6) & 63;    // max y0 in tile
        int rlo, rhi;
        if (lvl == 0)      { rlo = bxt * 2;        rhi = rlo + 1; }
        else if (lvl == 1) { rlo = (bxt - 32) * 4; rhi = rlo + 3; }
        else               { rlo = (bxt - 40) * 8; rhi = rlo + 7; }
        if (rhi < yF - 4 || rlo > yL + 5) return;    // v in [0,9] impossible
    }

    const int tid  = threadIdx.x;
    const int lane = tid & 63;
    const int wv   = tid >> 6;              // 0..7
    const int wr   = wv >> 1;               // 0..3: rows wr*64..+64
    const int wc   = wv & 1;                // 0..1: cols wc*64..+64
    const int ln15 = lane & 15;
    const int g4   = lane >> 4;

    const ushort_t* Bb = Bm + ((size_t)z * MPAD + (size_t)mbase) * ND;

    f4 acc[4][4] = {};

    // staging: A rows gathered through perm (per-lane global sources)
    const int rA  = tid >> 2;               // sorted row 0..127 (and +128)
    const int chA = (tid & 3) ^ ((tid >> 3) & 3);   // inverse-swizzled 16B chunk
    const int* pm = perm + (size_t)z * NQ + by * 256;
    const ushort_t* srcA0 = A + ((size_t)z * NQ + pm[rA])       * ND + chA * 8;
    const ushort_t* srcA1 = A + ((size_t)z * NQ + pm[128 + rA]) * ND + chA * 8;
    const ushort_t* srcB  = Bb + (size_t)rA * ND + chA * 8;     // B row = rA (0..127)

#define STAGE(buf, kk) {                                                   \
    gload_lds16(srcA0 + (kk), &As[buf][tid * 8]);                          \
    gload_lds16(srcA1 + (kk), &As[buf][(512 + tid) * 8]);                  \
    gload_lds16(srcB  + (kk), &Bs[buf][tid * 8]); }

    const int kch = (g4 ^ ((ln15 >> 1) & 3)) * 8;   // swizzled read slot

    STAGE(0, 0);
    STAGE(1, 32);
    STAGE(2, 64);

#pragma unroll
    for (int t = 0; t < 8; ++t) {
        const int cur = t % 3;
        // needed slot's loads are 2 K-steps old -> near-zero stall
        if (t < 6)       { asm volatile("s_waitcnt vmcnt(6)" ::: "memory"); }
        else if (t == 6) { asm volatile("s_waitcnt vmcnt(3)" ::: "memory"); }
        else             { asm volatile("s_waitcnt vmcnt(0)" ::: "memory"); }
        __builtin_amdgcn_s_barrier();        // #1: slot `cur` fully staged
        asm volatile("" ::: "memory");

        bfrag a[4], bb[4];
#pragma unroll
        for (int mi = 0; mi < 4; mi++)
            a[mi] = *reinterpret_cast<const bfrag*>(
                &As[cur][(wr * 64 + mi * 16 + ln15) * 32 + kch]);
#pragma unroll
        for (int ni = 0; ni < 4; ni++)
            bb[ni] = *reinterpret_cast<const bfrag*>(
                &Bs[cur][(wc * 64 + ni * 16 + ln15) * 32 + kch]);

        if (t < 5) {
            __builtin_amdgcn_sched_barrier(0);                    // pin ds_reads above
            asm volatile("s_waitcnt lgkmcnt(0)" ::: "memory");    // my reads complete
            __builtin_amdgcn_s_barrier();     // #2: all waves done reading slot `cur`
            asm volatile("" ::: "memory");
            STAGE(cur, (t + 3) * 32);         // overwrite slot `cur` with K-step t+3
        }

#pragma unroll
        for (int mi = 0; mi < 4; mi++)
#pragma unroll
            for (int ni = 0; ni < 4; ni++)
                acc[mi][ni] = __builtin_amdgcn_mfma_f32_16x16x32_bf16(
                    a[mi], bb[ni], acc[mi][ni], 0, 0, 0);
    }
#undef STAGE

    // ---- compacted epilogue, geometry-aware per level (sorted rows) ----
    const int row_base = by * 256 + wr * 64 + (g4 << 2);
    ushort_t* cmp      = compact + (size_t)z * NQ * 400 + lvl * 100;

    auto for_q = [&](auto body) {
#pragma unroll
        for (int mi = 0; mi < 4; mi++) {
            const int q0 = row_base + mi * 16;
            const int4 xy4 = *reinterpret_cast<const int4*>(&tbL[q0]);
            const int xys[4] = {xy4.x, xy4.y, xy4.z, xy4.w};
#pragma unroll
            for (int j = 0; j < 4; j++) {
                const int e = xys[j];
                body(mi, j, e & 63, (e >> 6) & 63, (size_t)((e >> 12) & 4095) * 400);
            }
        }
    };

    if (lvl == 0) {
        const int yfix = bxt * 2 + wc;           // y constant per thread
        for_q([&](int mi, int j, int x0, int y0, size_t qb) {
            unsigned v = (unsigned)(yfix - y0 + 4);
            if (v < 10u) {
                size_t vb = qb + v * 10;
#pragma unroll
                for (int ni = 0; ni < 4; ni++) {
                    unsigned u = (unsigned)(ln15 + 16 * ni + 4 - x0);
                    if (u < 10u) cmp[vb + u] = f2bf(acc[mi][ni][j]);
                }
            }
        });
    } else if (lvl == 1) {
        const int ybase = (bxt - 32) * 4 + wc * 2;
        for_q([&](int mi, int j, int x0, int y0, size_t qb) {
            unsigned u0 = (unsigned)(ln15 + 4 - x0), u1 = u0 + 16u;
            unsigned v0 = (unsigned)(ybase - y0 + 4), v1 = v0 + 1u;
            if (v0 < 10u) {
                if (u0 < 10u) cmp[qb + v0 * 10 + u0] = f2bf(acc[mi][0][j]);
                if (u1 < 10u) cmp[qb + v0 * 10 + u1] = f2bf(acc[mi][1][j]);
            }
            if (v1 < 10u) {
                if (u0 < 10u) cmp[qb + v1 * 10 + u0] = f2bf(acc[mi][2][j]);
                if (u1 < 10u) cmp[qb + v1 * 10 + u1] = f2bf(acc[mi][3][j]);
            }
        });
    } else if (lvl == 2) {
        const int ybase = (bxt - 40) * 8 + wc * 4;
        for_q([&](int mi, int j, int x0, int y0, size_t qb) {
            unsigned u = (unsigned)(ln15 + 4 - x0);
            if (u < 10u) {
#pragma unroll
                for (int ni = 0; ni < 4; ni++) {
                    unsigned v = (unsigned)(ybase + ni - y0 + 4);
                    if (v < 10u) cmp[qb + v * 10 + u] = f2bf(acc[mi][ni][j]);
                }
            }
        });
    } else if (wc == 0) {                        // lvl 3: cols 64..127 are pad
        const int yb3 = ln15 >> 3;
        for_q([&](int mi, int j, int x0, int y0, size_t qb) {
            unsigned u = (unsigned)((ln15 & 7) + 4 - x0);
            if (u < 10u) {
#pragma unroll
                for (int ni = 0; ni < 4; ni++) {
                    unsigned v = (unsigned)(yb3 + 2 * ni - y0 + 4);
                    if (v < 10u) cmp[qb + v * 10 + u] = f2bf(acc[mi][ni][j]);
                }
            }
        });
    }
}

// ---------- kernel 4: bilinear sampling, all 4 levels per block ----------
// grid (256, NB); block = 256 threads handles 16 queries x 4 levels
__global__ __launch_bounds__(256) void sample_kernel(
    const ushort_t* __restrict__ compact,  // [NB][4096][400] bf16
    const float* __restrict__ coords,
    float* __restrict__ out)               // [NB][324][64][64] f32
{
    __shared__ float Dl[16][404];
    __shared__ int   X0s[4][16], Y0s[4][16];
    __shared__ float wxs[4][16], wys[4][16];
    const int tid = threadIdx.x;
    const int g   = blockIdx.x;
    const int b   = blockIdx.y;

    if (tid < 64) {
        int qi = tid & 15, lvl = tid >> 4;
        int q = g * 16 + qi;
        float cx = coords[(size_t)(b * 2 + 0) * NQ + q];
        float cy = coords[(size_t)(b * 2 + 1) * NQ + q];
        float s = 1.0f / (float)(1 << lvl);
        float xl = cx * s, yl = cy * s;
        float fx = floorf(xl), fy = floorf(yl);
        X0s[lvl][qi] = (int)fx;
        Y0s[lvl][qi] = (int)fy;
        wxs[lvl][qi] = xl - fx;
        wys[lvl][qi] = yl - fy;
    }
    __syncthreads();

    // stage 16 queries x 400 cells (contiguous 800B per query)
#pragma unroll
    for (int r = 0; r < 25; r++) {
        int e = r * 256 + tid;             // 0..6399
        int qi = e / 400;
        int el = e - qi * 400;
        int lvl = el / 100;
        int le = el - lvl * 100;
        int v = le / 10, u = le - v * 10;
        int xx = X0s[lvl][qi] - 4 + u;
        int yy = Y0s[lvl][qi] - 4 + v;
        int Wl = 64 >> lvl;
        float val = 0.f;
        if ((unsigned)xx < (unsigned)Wl && (unsigned)yy < (unsigned)Wl)
            val = bf2f(compact[((size_t)b * NQ + g * 16 + qi) * 400 + el]);
        Dl[qi][lvl * 101 + le] = val;
    }
    __syncthreads();

    // 4 lvl x 81 c x 16 qi = 5184 outputs
#pragma unroll
    for (int r = 0; r < 21; r++) {
        int e = r * 256 + tid;
        if (e < 5184) {
            int lvl = e / 1296;
            int rem = e - lvl * 1296;
            int c  = rem >> 4;             // 0..80
            int qi = rem & 15;
            int i = c / 9;                 // x-offset grid index
            int j = c - i * 9;             // y-offset grid index
            float wx = wxs[lvl][qi], wy = wys[lvl][qi];
            const float* dq = &Dl[qi][lvl * 101];
            float d00 = dq[j * 10 + i];
            float d10 = dq[j * 10 + i + 1];
            float d01 = dq[(j + 1) * 10 + i];
            float d11 = dq[(j + 1) * 10 + i + 1];
            float vx0 = d00 + wx * (d10 - d00);
            float vx1 = d01 + wx * (d11 - d01);
            out[((size_t)b * NCH + lvl * 81 + c) * NQ + g * 16 + qi]
                = vx0 + wy * (vx1 - vx0);
        }
    }
}

extern "C" void kernel_launch(void* const* d_in, const int* in_sizes, int n_in,
                              void* d_out, int out_size, void* d_ws, size_t ws_size,
                              hipStream_t stream)
{
    const float* fmap1  = (const float*)d_in[0];
    const float* fmap2  = (const float*)d_in[1];
    const float* coords = (const float*)d_in[2];
    float* out = (float*)d_out;

    char* ws = (char*)d_ws;
    const size_t A_BYTES   = (size_t)NB * NQ * ND * 2;      //  8.4 MB
    const size_t B_BYTES   = (size_t)NB * MPAD * ND * 2;    // 11.3 MB
    const size_t CMP_BYTES = (size_t)NB * NQ * 400 * 2;     // 13.1 MB
    const size_t TBL_BYTES = (size_t)NB * 4 * NQ * 4;       //  256 KB
    ushort_t* Abf  = (ushort_t*)ws;
    ushort_t* Ball = (ushort_t*)(ws + A_BYTES);
    ushort_t* cmp  = (ushort_t*)(ws + A_BYTES + B_BYTES);
    int*      tblS = (int*)(ws + A_BYTES + B_BYTES + CMP_BYTES);
    int*      perm = (int*)(ws + A_BYTES + B_BYTES + CMP_BYTES + TBL_BYTES);

    sort_kernel<<<NB, 256, 0, stream>>>(coords, perm, tblS);

    pre_kernel<<<dim3(64, 4, 8), 256, 0, stream>>>(fmap1, fmap2, Abf, Ball);

    pool_fused<<<NB * 64, 256, 0, stream>>>(Ball);

    gemm_corr<<<dim3(16 * 43 * NB), 512, 0, stream>>>(Abf, Ball, cmp, perm, tblS);

    sample_kernel<<<dim3(256, NB), 256, 0, stream>>>(cmp, coords, out);
}

// Round 17
// 70.811 us; speedup vs baseline: 1.0821x; 1.0821x over previous
//
#include <hip/hip_runtime.h>

typedef unsigned short ushort_t;
typedef __attribute__((ext_vector_type(8))) short bfrag;
typedef __attribute__((ext_vector_type(4))) float f4;

// B=4, D=256, H=W=64, num_levels=4, radius=4
#define NB 4
#define ND 256
#define NH 64
#define NW 64
#define NQ (NH * NW)            // 4096 queries per batch
#define MPAD 5504               // 43 * 128 rows of pooled-f2 features
#define NLVL 4
#define NCH (NLVL * 81)

__device__ __forceinline__ float bf2f(ushort_t u) {
    return __uint_as_float(((unsigned)u) << 16);
}
__device__ __forceinline__ ushort_t f2bf(float f) {
    unsigned u = __float_as_uint(f);
    unsigned r = (u + 0x7fffu + ((u >> 16) & 1u)) >> 16;
    return (ushort_t)r;
}

__device__ __forceinline__ void gload_lds16(const void* g, void* l) {
    __builtin_amdgcn_global_load_lds(
        (const __attribute__((address_space(1))) unsigned int*)g,
        (__attribute__((address_space(3))) unsigned int*)l, 16, 0, 0);
}

// ---------- kernel 0: counting sort by y0 -> perm + sorted level tables ----------
// one block per batch; 256 threads, 16 queries each (wave-parallel bin scan)
__global__ __launch_bounds__(256) void sort_kernel(
    const float* __restrict__ coords,
    int* __restrict__ perm,             // [NB][4096] sorted pos -> true q
    int* __restrict__ tblS)             // [NB][4][4096] x0 | y0<<6 | q<<12 (sorted)
{
    __shared__ int hist[64];
    __shared__ int base[64];
    const int tid = threadIdx.x;
    const int b   = blockIdx.x;
    if (tid < 64) hist[tid] = 0;
    __syncthreads();
    int   keys[16];
    float cxs[16], cys[16];
#pragma unroll
    for (int i = 0; i < 16; i++) {
        int q = tid + i * 256;
        cxs[i] = coords[((size_t)b * 2 + 0) * NQ + q];
        cys[i] = coords[((size_t)b * 2 + 1) * NQ + q];
        keys[i] = (int)floorf(cys[i]);
        atomicAdd(&hist[keys[i]], 1);
    }
    __syncthreads();
    if (tid < 64) {                     // wave-parallel exclusive scan over 64 bins
        int v = hist[tid];
        int s = v;
#pragma unroll
        for (int off = 1; off < 64; off <<= 1) {
            int o = __shfl_up(s, off);
            if (tid >= off) s += o;
        }
        base[tid] = s - v;
    }
    __syncthreads();
#pragma unroll
    for (int i = 0; i < 16; i++) {
        int q = tid + i * 256;
        int pos = atomicAdd(&base[keys[i]], 1);
        perm[(size_t)b * NQ + pos] = q;
#pragma unroll
        for (int lvl = 0; lvl < 4; lvl++) {
            float s = 1.0f / (float)(1 << lvl);
            int x0 = (int)floorf(cxs[i] * s);
            int y0 = (int)floorf(cys[i] * s);
            tblS[(((size_t)b * 4 + lvl) << 12) + pos] = x0 | (y0 << 6) | (q << 12);
        }
    }
}

// ---------- kernel 1: fused transposes (linear writes) ----------
// z 0..3: fmap1 -> Abf (scaled 1/16); z 4..7: fmap2 -> Ball
__global__ __launch_bounds__(256) void pre_kernel(
    const float* __restrict__ f1, const float* __restrict__ f2,
    ushort_t* __restrict__ Abf, ushort_t* __restrict__ Ball)
{
    __shared__ float tile[64][65];
    const int tid = threadIdx.x;
    const int z = blockIdx.z;
    const int b = z & 3;
    const bool isA = (z < 4);
    const float* ib = (isA ? f1 : f2) + (size_t)b * ND * NQ;
    ushort_t* ob = isA ? (Abf + (size_t)b * NQ * ND) : (Ball + (size_t)b * MPAD * ND);
    const float scale = isA ? 0.0625f : 1.0f;
    const int n0 = blockIdx.x * 64, d0 = blockIdx.y * 64;
    const int nl = tid & 63, dg = tid >> 6;
#pragma unroll
    for (int i = 0; i < 16; i++) {
        int dl = dg + i * 4;
        tile[dl][nl] = ib[(size_t)(d0 + dl) * NQ + n0 + nl];
    }
    __syncthreads();
    const int dl = tid & 63, ng = tid >> 6;
#pragma unroll
    for (int i = 0; i < 16; i++) {
        int nn = ng + i * 4;
        ob[(size_t)(n0 + nn) * ND + d0 + dl] = f2bf(tile[dl][nn] * scale);
    }
}

// ---------- kernel 2: all 3 pyramid levels in one pass ----------
__global__ __launch_bounds__(256) void pool_fused(ushort_t* __restrict__ Ball)
{
    const int d = threadIdx.x;
    const int bid = blockIdx.x;          // 0 .. NB*64-1
    const int b = bid >> 6;
    const int cell = bid & 63;
    const int Y = cell >> 3, X = cell & 7;
    ushort_t* base = Ball + (size_t)b * MPAD * ND;

    float s1[4][4];
#pragma unroll
    for (int iy = 0; iy < 4; iy++)
#pragma unroll
        for (int ix = 0; ix < 4; ix++) {
            int ry = 2 * (4 * Y + iy), rx = 2 * (4 * X + ix);
            float s = bf2f(base[(size_t)((ry    ) * 64 + rx    ) * ND + d])
                    + bf2f(base[(size_t)((ry    ) * 64 + rx + 1) * ND + d])
                    + bf2f(base[(size_t)((ry + 1) * 64 + rx    ) * ND + d])
                    + bf2f(base[(size_t)((ry + 1) * 64 + rx + 1) * ND + d]);
            s1[iy][ix] = s * 0.25f;
            base[(size_t)(4096 + (4 * Y + iy) * 32 + 4 * X + ix) * ND + d] = f2bf(s1[iy][ix]);
        }
    float s2[2][2];
#pragma unroll
    for (int iy = 0; iy < 2; iy++)
#pragma unroll
        for (int ix = 0; ix < 2; ix++) {
            float s = 0.25f * (s1[2*iy][2*ix] + s1[2*iy][2*ix+1]
                             + s1[2*iy+1][2*ix] + s1[2*iy+1][2*ix+1]);
            s2[iy][ix] = s;
            base[(size_t)(5120 + (2 * Y + iy) * 16 + 2 * X + ix) * ND + d] = f2bf(s);
        }
    float s3 = 0.25f * (s2[0][0] + s2[0][1] + s2[1][0] + s2[1][1]);
    base[(size_t)(5376 + Y * 8 + X) * ND + d] = f2bf(s3);
}

// ---------- kernel 3: R13 GEMM (A gathered via perm) + sorted-query early exit ----------
// grid.x = 2752 = 4 batches * 16 M-tiles * 43 col-tiles, XCD-swizzled
__global__ __launch_bounds__(512, 4) void gemm_corr(
    const ushort_t* __restrict__ A,     // [NB][4096][256] bf16 (pre-scaled by 1/16)
    const ushort_t* __restrict__ Bm,    // [NB][MPAD][256] bf16
    ushort_t* __restrict__ compact,     // [NB][4096][400] bf16
    const int* __restrict__ perm,       // [NB][4096] sorted pos -> true q
    const int* __restrict__ tblS)       // [NB][4][4096] x0 | y0<<6 | q<<12 (sorted)
{
    __shared__ ushort_t As[3][256 * 32];    // 48 KiB
    __shared__ ushort_t Bs[3][128 * 32];    // 24 KiB

    // bijective XCD-chunk swizzle: 2752 = 8 * 344
    const int l   = blockIdx.x;
    const int wg  = (l & 7) * 344 + (l >> 3);
    const int z   = wg / 688;
    const int rem = wg - z * 688;
    const int by  = rem / 43;               // 0..15 (256-row M tiles)
    const int bxt = rem - by * 43;          // 0..42 (128-col tiles)

    int lvl, mbase;
    if (bxt < 32)      { lvl = 0; mbase = bxt * 128; }
    else if (bxt < 40) { lvl = 1; mbase = 4096 + (bxt - 32) * 128; }
    else if (bxt < 42) { lvl = 2; mbase = 5120 + (bxt - 40) * 128; }
    else               { lvl = 3; mbase = 5376; }

    const int* tbL = tblS + (((size_t)z * 4 + lvl) << 12);   // this level, sorted

    // ---- early exit: do my y-rows intersect any query's 10-wide window? ----
    if (lvl < 3) {
        int yF = (tbL[by * 256] >> 6) & 63;          // min y0 in tile (sorted)
        int yL = (tbL[by * 256 + 255] >> 6) & 63;    // max y0 in tile
        int rlo, rhi;
        if (lvl == 0)      { rlo = bxt * 2;        rhi = rlo + 1; }
        else if (lvl == 1) { rlo = (bxt - 32) * 4; rhi = rlo + 3; }
        else               { rlo = (bxt - 40) * 8; rhi = rlo + 7; }
        if (rhi < yF - 4 || rlo > yL + 5) return;    // v in [0,9] impossible
    }

    const int tid  = threadIdx.x;
    const int lane = tid & 63;
    const int wv   = tid >> 6;              // 0..7
    const int wr   = wv >> 1;               // 0..3: rows wr*64..+64
    const int wc   = wv & 1;                // 0..1: cols wc*64..+64
    const int ln15 = lane & 15;
    const int g4   = lane >> 4;

    const ushort_t* Bb = Bm + ((size_t)z * MPAD + (size_t)mbase) * ND;

    f4 acc[4][4] = {};

    // staging: A rows gathered through perm (per-lane global sources)
    const int rA  = tid >> 2;               // sorted row 0..127 (and +128)
    const int chA = (tid & 3) ^ ((tid >> 3) & 3);   // inverse-swizzled 16B chunk
    const int* pm = perm + (size_t)z * NQ + by * 256;
    const ushort_t* srcA0 = A + ((size_t)z * NQ + pm[rA])       * ND + chA * 8;
    const ushort_t* srcA1 = A + ((size_t)z * NQ + pm[128 + rA]) * ND + chA * 8;
    const ushort_t* srcB  = Bb + (size_t)rA * ND + chA * 8;     // B row = rA (0..127)

#define STAGE(buf, kk) {                                                   \
    gload_lds16(srcA0 + (kk), &As[buf][tid * 8]);                          \
    gload_lds16(srcA1 + (kk), &As[buf][(512 + tid) * 8]);                  \
    gload_lds16(srcB  + (kk), &Bs[buf][tid * 8]); }

    const int kch = (g4 ^ ((ln15 >> 1) & 3)) * 8;   // swizzled read slot

    STAGE(0, 0);
    STAGE(1, 32);
    STAGE(2, 64);

#pragma unroll
    for (int t = 0; t < 8; ++t) {
        const int cur = t % 3;
        // needed slot's loads are 2 K-steps old -> near-zero stall
        if (t < 6)       { asm volatile("s_waitcnt vmcnt(6)" ::: "memory"); }
        else if (t == 6) { asm volatile("s_waitcnt vmcnt(3)" ::: "memory"); }
        else             { asm volatile("s_waitcnt vmcnt(0)" ::: "memory"); }
        __builtin_amdgcn_s_barrier();        // #1: slot `cur` fully staged
        asm volatile("" ::: "memory");

        bfrag a[4], bb[4];
#pragma unroll
        for (int mi = 0; mi < 4; mi++)
            a[mi] = *reinterpret_cast<const bfrag*>(
                &As[cur][(wr * 64 + mi * 16 + ln15) * 32 + kch]);
#pragma unroll
        for (int ni = 0; ni < 4; ni++)
            bb[ni] = *reinterpret_cast<const bfrag*>(
                &Bs[cur][(wc * 64 + ni * 16 + ln15) * 32 + kch]);

        if (t < 5) {
            __builtin_amdgcn_sched_barrier(0);                    // pin ds_reads above
            asm volatile("s_waitcnt lgkmcnt(0)" ::: "memory");    // my reads complete
            __builtin_amdgcn_s_barrier();     // #2: all waves done reading slot `cur`
            asm volatile("" ::: "memory");
            STAGE(cur, (t + 3) * 32);         // overwrite slot `cur` with K-step t+3
        }

#pragma unroll
        for (int mi = 0; mi < 4; mi++)
#pragma unroll
            for (int ni = 0; ni < 4; ni++)
                acc[mi][ni] = __builtin_amdgcn_mfma_f32_16x16x32_bf16(
                    a[mi], bb[ni], acc[mi][ni], 0, 0, 0);
    }
#undef STAGE

    // ---- compacted epilogue, geometry-aware per level (sorted rows) ----
    const int row_base = by * 256 + wr * 64 + (g4 << 2);
    ushort_t* cmp      = compact + (size_t)z * NQ * 400 + lvl * 100;

    auto for_q = [&](auto body) {
#pragma unroll
        for (int mi = 0; mi < 4; mi++) {
            const int q0 = row_base + mi * 16;
            const int4 xy4 = *reinterpret_cast<const int4*>(&tbL[q0]);
            const int xys[4] = {xy4.x, xy4.y, xy4.z, xy4.w};
#pragma unroll
            for (int j = 0; j < 4; j++) {
                const int e = xys[j];
                body(mi, j, e & 63, (e >> 6) & 63, (size_t)((e >> 12) & 4095) * 400);
            }
        }
    };

    if (lvl == 0) {
        const int yfix = bxt * 2 + wc;           // y constant per thread
        for_q([&](int mi, int j, int x0, int y0, size_t qb) {
            unsigned v = (unsigned)(yfix - y0 + 4);
            if (v < 10u) {
                size_t vb = qb + v * 10;
#pragma unroll
                for (int ni = 0; ni < 4; ni++) {
                    unsigned u = (unsigned)(ln15 + 16 * ni + 4 - x0);
                    if (u < 10u) cmp[vb + u] = f2bf(acc[mi][ni][j]);
                }
            }
        });
    } else if (lvl == 1) {
        const int ybase = (bxt - 32) * 4 + wc * 2;
        for_q([&](int mi, int j, int x0, int y0, size_t qb) {
            unsigned u0 = (unsigned)(ln15 + 4 - x0), u1 = u0 + 16u;
            unsigned v0 = (unsigned)(ybase - y0 + 4), v1 = v0 + 1u;
            if (v0 < 10u) {
                if (u0 < 10u) cmp[qb + v0 * 10 + u0] = f2bf(acc[mi][0][j]);
                if (u1 < 10u) cmp[qb + v0 * 10 + u1] = f2bf(acc[mi][1][j]);
            }
            if (v1 < 10u) {
                if (u0 < 10u) cmp[qb + v1 * 10 + u0] = f2bf(acc[mi][2][j]);
                if (u1 < 10u) cmp[qb + v1 * 10 + u1] = f2bf(acc[mi][3][j]);
            }
        });
    } else if (lvl == 2) {
        const int ybase = (bxt - 40) * 8 + wc * 4;
        for_q([&](int mi, int j, int x0, int y0, size_t qb) {
            unsigned u = (unsigned)(ln15 + 4 - x0);
            if (u < 10u) {
#pragma unroll
                for (int ni = 0; ni < 4; ni++) {
                    unsigned v = (unsigned)(ybase + ni - y0 + 4);
                    if (v < 10u) cmp[qb + v * 10 + u] = f2bf(acc[mi][ni][j]);
                }
            }
        });
    } else if (wc == 0) {                        // lvl 3: cols 64..127 are pad
        const int yb3 = ln15 >> 3;
        for_q([&](int mi, int j, int x0, int y0, size_t qb) {
            unsigned u = (unsigned)((ln15 & 7) + 4 - x0);
            if (u < 10u) {
#pragma unroll
                for (int ni = 0; ni < 4; ni++) {
                    unsigned v = (unsigned)(yb3 + 2 * ni - y0 + 4);
                    if (v < 10u) cmp[qb + v * 10 + u] = f2bf(acc[mi][ni][j]);
                }
            }
        });
    }
}

// ---------- kernel 4: bilinear sampling from the compact window buffer ----------
// block = 256 threads handles 16 queries x 1 level; grid (256 qgroups, 4 levels, NB)
__global__ __launch_bounds__(256) void sample_kernel(
    const ushort_t* __restrict__ compact,  // [NB][4096][400] bf16
    const float* __restrict__ coords,
    float* __restrict__ out)               // [NB][324][64][64] f32
{
    __shared__ int   X0s[16], Y0s[16];
    __shared__ float wxs[16], wys[16];
    __shared__ float Dl[16 * 101];
    const int tid = threadIdx.x;
    const int g   = blockIdx.x;
    const int lvl = blockIdx.y;
    const int b   = blockIdx.z;
    const int Wl  = NW >> lvl;

    if (tid < 16) {
        int q = g * 16 + tid;
        float cx = coords[(size_t)(b * 2 + 0) * NQ + q];
        float cy = coords[(size_t)(b * 2 + 1) * NQ + q];
        float s = 1.0f / (float)(1 << lvl);
        float xl = cx * s, yl = cy * s;
        float fx = floorf(xl), fy = floorf(yl);
        X0s[tid] = (int)fx;
        Y0s[tid] = (int)fy;
        wxs[tid] = xl - fx;
        wys[tid] = yl - fy;
    }
    __syncthreads();

#pragma unroll
    for (int r = 0; r < 7; r++) {
        int e = r * 256 + tid;
        if (e < 16 * 100) {
            int qi = e / 100;
            int el = e - qi * 100;
            int v = el / 10;
            int u = el - v * 10;
            int xx = X0s[qi] - 4 + u;
            int yy = Y0s[qi] - 4 + v;
            float val = 0.f;
            if ((unsigned)xx < (unsigned)Wl && (unsigned)yy < (unsigned)Wl)
                val = bf2f(compact[((size_t)b * NQ + g * 16 + qi) * 400
                                   + lvl * 100 + el]);
            Dl[qi * 101 + el] = val;
        }
    }
    __syncthreads();

#pragma unroll
    for (int r = 0; r < 6; r++) {
        int e = r * 256 + tid;
        if (e < 16 * 81) {
            int qi = e & 15;
            int c = e >> 4;
            int i = c / 9;            // x-offset grid index
            int j = c - i * 9;        // y-offset grid index
            float wx = wxs[qi], wy = wys[qi];
            const float* dq = &Dl[qi * 101];
            float d00 = dq[j * 10 + i];
            float d10 = dq[j * 10 + i + 1];
            float d01 = dq[(j + 1) * 10 + i];
            float d11 = dq[(j + 1) * 10 + i + 1];
            float vx0 = d00 + wx * (d10 - d00);
            float vx1 = d01 + wx * (d11 - d01);
            float val = vx0 + wy * (vx1 - vx0);
            out[((size_t)b * NCH + lvl * 81 + c) * NQ + g * 16 + qi] = val;
        }
    }
}

extern "C" void kernel_launch(void* const* d_in, const int* in_sizes, int n_in,
                              void* d_out, int out_size, void* d_ws, size_t ws_size,
                              hipStream_t stream)
{
    const float* fmap1  = (const float*)d_in[0];
    const float* fmap2  = (const float*)d_in[1];
    const float* coords = (const float*)d_in[2];
    float* out = (float*)d_out;

    char* ws = (char*)d_ws;
    const size_t A_BYTES   = (size_t)NB * NQ * ND * 2;      //  8.4 MB
    const size_t B_BYTES   = (size_t)NB * MPAD * ND * 2;    // 11.3 MB
    const size_t CMP_BYTES = (size_t)NB * NQ * 400 * 2;     // 13.1 MB
    const size_t TBL_BYTES = (size_t)NB * 4 * NQ * 4;       //  256 KB
    ushort_t* Abf  = (ushort_t*)ws;
    ushort_t* Ball = (ushort_t*)(ws + A_BYTES);
    ushort_t* cmp  = (ushort_t*)(ws + A_BYTES + B_BYTES);
    int*      tblS = (int*)(ws + A_BYTES + B_BYTES + CMP_BYTES);
    int*      perm = (int*)(ws + A_BYTES + B_BYTES + CMP_BYTES + TBL_BYTES);

    sort_kernel<<<NB, 256, 0, stream>>>(coords, perm, tblS);

    pre_kernel<<<dim3(64, 4, 8), 256, 0, stream>>>(fmap1, fmap2, Abf, Ball);

    pool_fused<<<NB * 64, 256, 0, stream>>>(Ball);

    gemm_corr<<<dim3(16 * 43 * NB), 512, 0, stream>>>(Abf, Ball, cmp, perm, tblS);

    sample_kernel<<<dim3(256, NLVL, NB), 256, 0, stream>>>(cmp, coords, out);
}

// Round 18
// 67.612 us; speedup vs baseline: 1.1333x; 1.0473x over previous
//
#include <hip/hip_runtime.h>

typedef unsigned short ushort_t;
typedef __attribute__((ext_vector_type(8))) short bfrag;
typedef __attribute__((ext_vector_type(4))) float f4;

// B=4, D=256, H=W=64, num_levels=4, radius=4
#define NB 4
#define ND 256
#define NH 64
#define NW 64
#define NQ (NH * NW)            // 4096 queries per batch
#define MPAD 5504               // 43 * 128 rows of pooled-f2 features
#define NLVL 4
#define NCH (NLVL * 81)

__device__ __forceinline__ float bf2f(ushort_t u) {
    return __uint_as_float(((unsigned)u) << 16);
}
__device__ __forceinline__ ushort_t f2bf(float f) {
    unsigned u = __float_as_uint(f);
    unsigned r = (u + 0x7fffu + ((u >> 16) & 1u)) >> 16;
    return (ushort_t)r;
}

__device__ __forceinline__ void gload_lds16(const void* g, void* l) {
    __builtin_amdgcn_global_load_lds(
        (const __attribute__((address_space(1))) unsigned int*)g,
        (__attribute__((address_space(3))) unsigned int*)l, 16, 0, 0);
}

// ---------- kernel 0: counting sort of queries by y0 = floor(cy), per batch ----------
__global__ __launch_bounds__(256) void sort_kernel(
    const float* __restrict__ coords, int* __restrict__ perm)
{
    __shared__ int hist[64];
    __shared__ int base[64];
    const int tid = threadIdx.x;
    const int b   = blockIdx.x;
    if (tid < 64) hist[tid] = 0;
    __syncthreads();
    int keys[16];
#pragma unroll
    for (int i = 0; i < 16; i++) {
        int q = tid + i * 256;
        float cy = coords[((size_t)b * 2 + 1) * NQ + q];
        keys[i] = (int)floorf(cy);
        atomicAdd(&hist[keys[i]], 1);
    }
    __syncthreads();
    if (tid < 64) {                     // wave-parallel exclusive scan over 64 bins
        int v = hist[tid];
        int s = v;
#pragma unroll
        for (int off = 1; off < 64; off <<= 1) {
            int o = __shfl_up(s, off);
            if (tid >= off) s += o;
        }
        base[tid] = s - v;
    }
    __syncthreads();
#pragma unroll
    for (int i = 0; i < 16; i++) {
        int q = tid + i * 256;
        int pos = atomicAdd(&base[keys[i]], 1);
        perm[(size_t)b * NQ + pos] = q;
    }
}

// ---------- kernel 0b: sorted per-level table: x0 | y0<<6 | q<<12 (coalesced writes) ----------
__global__ __launch_bounds__(256) void tbls_kernel(
    const float* __restrict__ coords, const int* __restrict__ perm,
    int* __restrict__ tblS)
{
    const int idx = blockIdx.x * 256 + threadIdx.x;    // b*4096 + pos
    const int b = idx >> 12, pos = idx & 4095;
    const int q = perm[(size_t)b * NQ + pos];
    const float cx = coords[((size_t)b * 2 + 0) * NQ + q];
    const float cy = coords[((size_t)b * 2 + 1) * NQ + q];
#pragma unroll
    for (int lvl = 0; lvl < 4; lvl++) {
        float s = 1.0f / (float)(1 << lvl);
        int x0 = (int)floorf(cx * s);
        int y0 = (int)floorf(cy * s);
        tblS[(((size_t)b * 4 + lvl) << 12) + pos] = x0 | (y0 << 6) | (q << 12);
    }
}

// ---------- kernel 1: fused transposes (linear writes) ----------
// z 0..3: fmap1 -> Abf (scaled 1/16); z 4..7: fmap2 -> Ball
__global__ __launch_bounds__(256) void pre_kernel(
    const float* __restrict__ f1, const float* __restrict__ f2,
    ushort_t* __restrict__ Abf, ushort_t* __restrict__ Ball)
{
    __shared__ float tile[64][65];
    const int tid = threadIdx.x;
    const int z = blockIdx.z;
    const int b = z & 3;
    const bool isA = (z < 4);
    const float* ib = (isA ? f1 : f2) + (size_t)b * ND * NQ;
    ushort_t* ob = isA ? (Abf + (size_t)b * NQ * ND) : (Ball + (size_t)b * MPAD * ND);
    const float scale = isA ? 0.0625f : 1.0f;
    const int n0 = blockIdx.x * 64, d0 = blockIdx.y * 64;
    const int nl = tid & 63, dg = tid >> 6;
#pragma unroll
    for (int i = 0; i < 16; i++) {
        int dl = dg + i * 4;
        tile[dl][nl] = ib[(size_t)(d0 + dl) * NQ + n0 + nl];
    }
    __syncthreads();
    const int dl = tid & 63, ng = tid >> 6;
#pragma unroll
    for (int i = 0; i < 16; i++) {
        int nn = ng + i * 4;
        ob[(size_t)(n0 + nn) * ND + d0 + dl] = f2bf(tile[dl][nn] * scale);
    }
}

// ---------- kernel 2: all 3 pyramid levels in one pass ----------
__global__ __launch_bounds__(256) void pool_fused(ushort_t* __restrict__ Ball)
{
    const int d = threadIdx.x;
    const int bid = blockIdx.x;          // 0 .. NB*64-1
    const int b = bid >> 6;
    const int cell = bid & 63;
    const int Y = cell >> 3, X = cell & 7;
    ushort_t* base = Ball + (size_t)b * MPAD * ND;

    float s1[4][4];
#pragma unroll
    for (int iy = 0; iy < 4; iy++)
#pragma unroll
        for (int ix = 0; ix < 4; ix++) {
            int ry = 2 * (4 * Y + iy), rx = 2 * (4 * X + ix);
            float s = bf2f(base[(size_t)((ry    ) * 64 + rx    ) * ND + d])
                    + bf2f(base[(size_t)((ry    ) * 64 + rx + 1) * ND + d])
                    + bf2f(base[(size_t)((ry + 1) * 64 + rx    ) * ND + d])
                    + bf2f(base[(size_t)((ry + 1) * 64 + rx + 1) * ND + d]);
            s1[iy][ix] = s * 0.25f;
            base[(size_t)(4096 + (4 * Y + iy) * 32 + 4 * X + ix) * ND + d] = f2bf(s1[iy][ix]);
        }
    float s2[2][2];
#pragma unroll
    for (int iy = 0; iy < 2; iy++)
#pragma unroll
        for (int ix = 0; ix < 2; ix++) {
            float s = 0.25f * (s1[2*iy][2*ix] + s1[2*iy][2*ix+1]
                             + s1[2*iy+1][2*ix] + s1[2*iy+1][2*ix+1]);
            s2[iy][ix] = s;
            base[(size_t)(5120 + (2 * Y + iy) * 16 + 2 * X + ix) * ND + d] = f2bf(s);
        }
    float s3 = 0.25f * (s2[0][0] + s2[0][1] + s2[1][0] + s2[1][1]);
    base[(size_t)(5376 + Y * 8 + X) * ND + d] = f2bf(s3);
}

// ---------- kernel 3: R13 GEMM (A gathered via perm) + sorted-query early exit ----------
// grid.x = 2752 = 4 batches * 16 M-tiles * 43 col-tiles, XCD-swizzled
__global__ __launch_bounds__(512, 4) void gemm_corr(
    const ushort_t* __restrict__ A,     // [NB][4096][256] bf16 (pre-scaled by 1/16)
    const ushort_t* __restrict__ Bm,    // [NB][MPAD][256] bf16
    ushort_t* __restrict__ compact,     // [NB][4096][400] bf16
    const int* __restrict__ perm,       // [NB][4096] sorted pos -> true q
    const int* __restrict__ tblS)       // [NB][4][4096] x0 | y0<<6 | q<<12 (sorted)
{
    __shared__ ushort_t As[3][256 * 32];    // 48 KiB
    __shared__ ushort_t Bs[3][128 * 32];    // 24 KiB

    // bijective XCD-chunk swizzle: 2752 = 8 * 344
    const int l   = blockIdx.x;
    const int wg  = (l & 7) * 344 + (l >> 3);
    const int z   = wg / 688;
    const int rem = wg - z * 688;
    const int by  = rem / 43;               // 0..15 (256-row M tiles)
    const int bxt = rem - by * 43;          // 0..42 (128-col tiles)

    int lvl, mbase;
    if (bxt < 32)      { lvl = 0; mbase = bxt * 128; }
    else if (bxt < 40) { lvl = 1; mbase = 4096 + (bxt - 32) * 128; }
    else if (bxt < 42) { lvl = 2; mbase = 5120 + (bxt - 40) * 128; }
    else               { lvl = 3; mbase = 5376; }

    const int* tbL = tblS + (((size_t)z * 4 + lvl) << 12);   // this level, sorted

    // ---- early exit: do my y-rows intersect any query's 10-wide window? ----
    if (lvl < 3) {
        int yF = (tbL[by * 256] >> 6) & 63;          // min y0 in tile (sorted)
        int yL = (tbL[by * 256 + 255] >> 6) & 63;    // max y0 in tile
        int rlo, rhi;
        if (lvl == 0)      { rlo = bxt * 2;        rhi = rlo + 1; }
        else if (lvl == 1) { rlo = (bxt - 32) * 4; rhi = rlo + 3; }
        else               { rlo = (bxt - 40) * 8; rhi = rlo + 7; }
        if (rhi < yF - 4 || rlo > yL + 5) return;    // v in [0,9] impossible
    }

    const int tid  = threadIdx.x;
    const int lane = tid & 63;
    const int wv   = tid >> 6;              // 0..7
    const int wr   = wv >> 1;               // 0..3: rows wr*64..+64
    const int wc   = wv & 1;                // 0..1: cols wc*64..+64
    const int ln15 = lane & 15;
    const int g4   = lane >> 4;

    const ushort_t* Bb = Bm + ((size_t)z * MPAD + (size_t)mbase) * ND;

    f4 acc[4][4] = {};

    // staging: A rows gathered through perm (per-lane global sources)
    const int rA  = tid >> 2;               // sorted row 0..127 (and +128)
    const int chA = (tid & 3) ^ ((tid >> 3) & 3);   // inverse-swizzled 16B chunk
    const int* pm = perm + (size_t)z * NQ + by * 256;
    const ushort_t* srcA0 = A + ((size_t)z * NQ + pm[rA])       * ND + chA * 8;
    const ushort_t* srcA1 = A + ((size_t)z * NQ + pm[128 + rA]) * ND + chA * 8;
    const ushort_t* srcB  = Bb + (size_t)rA * ND + chA * 8;     // B row = rA (0..127)

#define STAGE(buf, kk) {                                                   \
    gload_lds16(srcA0 + (kk), &As[buf][tid * 8]);                          \
    gload_lds16(srcA1 + (kk), &As[buf][(512 + tid) * 8]);                  \
    gload_lds16(srcB  + (kk), &Bs[buf][tid * 8]); }

    const int kch = (g4 ^ ((ln15 >> 1) & 3)) * 8;   // swizzled read slot

    STAGE(0, 0);
    STAGE(1, 32);
    STAGE(2, 64);

#pragma unroll
    for (int t = 0; t < 8; ++t) {
        const int cur = t % 3;
        // needed slot's loads are 2 K-steps old -> near-zero stall
        if (t < 6)       { asm volatile("s_waitcnt vmcnt(6)" ::: "memory"); }
        else if (t == 6) { asm volatile("s_waitcnt vmcnt(3)" ::: "memory"); }
        else             { asm volatile("s_waitcnt vmcnt(0)" ::: "memory"); }
        __builtin_amdgcn_s_barrier();        // #1: slot `cur` fully staged
        asm volatile("" ::: "memory");

        bfrag a[4], bb[4];
#pragma unroll
        for (int mi = 0; mi < 4; mi++)
            a[mi] = *reinterpret_cast<const bfrag*>(
                &As[cur][(wr * 64 + mi * 16 + ln15) * 32 + kch]);
#pragma unroll
        for (int ni = 0; ni < 4; ni++)
            bb[ni] = *reinterpret_cast<const bfrag*>(
                &Bs[cur][(wc * 64 + ni * 16 + ln15) * 32 + kch]);

        if (t < 5) {
            __builtin_amdgcn_sched_barrier(0);                    // pin ds_reads above
            asm volatile("s_waitcnt lgkmcnt(0)" ::: "memory");    // my reads complete
            __builtin_amdgcn_s_barrier();     // #2: all waves done reading slot `cur`
            asm volatile("" ::: "memory");
            STAGE(cur, (t + 3) * 32);         // overwrite slot `cur` with K-step t+3
        }

#pragma unroll
        for (int mi = 0; mi < 4; mi++)
#pragma unroll
            for (int ni = 0; ni < 4; ni++)
                acc[mi][ni] = __builtin_amdgcn_mfma_f32_16x16x32_bf16(
                    a[mi], bb[ni], acc[mi][ni], 0, 0, 0);
    }
#undef STAGE

    // ---- compacted epilogue, geometry-aware per level (sorted rows) ----
    const int row_base = by * 256 + wr * 64 + (g4 << 2);
    ushort_t* cmp      = compact + (size_t)z * NQ * 400 + lvl * 100;

    auto for_q = [&](auto body) {
#pragma unroll
        for (int mi = 0; mi < 4; mi++) {
            const int q0 = row_base + mi * 16;
            const int4 xy4 = *reinterpret_cast<const int4*>(&tbL[q0]);
            const int xys[4] = {xy4.x, xy4.y, xy4.z, xy4.w};
#pragma unroll
            for (int j = 0; j < 4; j++) {
                const int e = xys[j];
                body(mi, j, e & 63, (e >> 6) & 63, (size_t)((e >> 12) & 4095) * 400);
            }
        }
    };

    if (lvl == 0) {
        const int yfix = bxt * 2 + wc;           // y constant per thread
        for_q([&](int mi, int j, int x0, int y0, size_t qb) {
            unsigned v = (unsigned)(yfix - y0 + 4);
            if (v < 10u) {
                size_t vb = qb + v * 10;
#pragma unroll
                for (int ni = 0; ni < 4; ni++) {
                    unsigned u = (unsigned)(ln15 + 16 * ni + 4 - x0);
                    if (u < 10u) cmp[vb + u] = f2bf(acc[mi][ni][j]);
                }
            }
        });
    } else if (lvl == 1) {
        const int ybase = (bxt - 32) * 4 + wc * 2;
        for_q([&](int mi, int j, int x0, int y0, size_t qb) {
            unsigned u0 = (unsigned)(ln15 + 4 - x0), u1 = u0 + 16u;
            unsigned v0 = (unsigned)(ybase - y0 + 4), v1 = v0 + 1u;
            if (v0 < 10u) {
                if (u0 < 10u) cmp[qb + v0 * 10 + u0] = f2bf(acc[mi][0][j]);
                if (u1 < 10u) cmp[qb + v0 * 10 + u1] = f2bf(acc[mi][1][j]);
            }
            if (v1 < 10u) {
                if (u0 < 10u) cmp[qb + v1 * 10 + u0] = f2bf(acc[mi][2][j]);
                if (u1 < 10u) cmp[qb + v1 * 10 + u1] = f2bf(acc[mi][3][j]);
            }
        });
    } else if (lvl == 2) {
        const int ybase = (bxt - 40) * 8 + wc * 4;
        for_q([&](int mi, int j, int x0, int y0, size_t qb) {
            unsigned u = (unsigned)(ln15 + 4 - x0);
            if (u < 10u) {
#pragma unroll
                for (int ni = 0; ni < 4; ni++) {
                    unsigned v = (unsigned)(ybase + ni - y0 + 4);
                    if (v < 10u) cmp[qb + v * 10 + u] = f2bf(acc[mi][ni][j]);
                }
            }
        });
    } else if (wc == 0) {                        // lvl 3: cols 64..127 are pad
        const int yb3 = ln15 >> 3;
        for_q([&](int mi, int j, int x0, int y0, size_t qb) {
            unsigned u = (unsigned)((ln15 & 7) + 4 - x0);
            if (u < 10u) {
#pragma unroll
                for (int ni = 0; ni < 4; ni++) {
                    unsigned v = (unsigned)(yb3 + 2 * ni - y0 + 4);
                    if (v < 10u) cmp[qb + v * 10 + u] = f2bf(acc[mi][ni][j]);
                }
            }
        });
    }
}

// ---------- kernel 4: bilinear sampling from the compact window buffer ----------
// block = 256 threads handles 16 queries x 1 level; grid (256 qgroups, 4 levels, NB)
__global__ __launch_bounds__(256) void sample_kernel(
    const ushort_t* __restrict__ compact,  // [NB][4096][400] bf16
    const float* __restrict__ coords,
    float* __restrict__ out)               // [NB][324][64][64] f32
{
    __shared__ int   X0s[16], Y0s[16];
    __shared__ float wxs[16], wys[16];
    __shared__ float Dl[16 * 101];
    const int tid = threadIdx.x;
    const int g   = blockIdx.x;
    const int lvl = blockIdx.y;
    const int b   = blockIdx.z;
    const int Wl  = NW >> lvl;

    if (tid < 16) {
        int q = g * 16 + tid;
        float cx = coords[(size_t)(b * 2 + 0) * NQ + q];
        float cy = coords[(size_t)(b * 2 + 1) * NQ + q];
        float s = 1.0f / (float)(1 << lvl);
        float xl = cx * s, yl = cy * s;
        float fx = floorf(xl), fy = floorf(yl);
        X0s[tid] = (int)fx;
        Y0s[tid] = (int)fy;
        wxs[tid] = xl - fx;
        wys[tid] = yl - fy;
    }
    __syncthreads();

#pragma unroll
    for (int r = 0; r < 7; r++) {
        int e = r * 256 + tid;
        if (e < 16 * 100) {
            int qi = e / 100;
            int el = e - qi * 100;
            int v = el / 10;
            int u = el - v * 10;
            int xx = X0s[qi] - 4 + u;
            int yy = Y0s[qi] - 4 + v;
            float val = 0.f;
            if ((unsigned)xx < (unsigned)Wl && (unsigned)yy < (unsigned)Wl)
                val = bf2f(compact[((size_t)b * NQ + g * 16 + qi) * 400
                                   + lvl * 100 + el]);
            Dl[qi * 101 + el] = val;
        }
    }
    __syncthreads();

#pragma unroll
    for (int r = 0; r < 6; r++) {
        int e = r * 256 + tid;
        if (e < 16 * 81) {
            int qi = e & 15;
            int c = e >> 4;
            int i = c / 9;            // x-offset grid index
            int j = c - i * 9;        // y-offset grid index
            float wx = wxs[qi], wy = wys[qi];
            const float* dq = &Dl[qi * 101];
            float d00 = dq[j * 10 + i];
            float d10 = dq[j * 10 + i + 1];
            float d01 = dq[(j + 1) * 10 + i];
            float d11 = dq[(j + 1) * 10 + i + 1];
            float vx0 = d00 + wx * (d10 - d00);
            float vx1 = d01 + wx * (d11 - d01);
            float val = vx0 + wy * (vx1 - vx0);
            out[((size_t)b * NCH + lvl * 81 + c) * NQ + g * 16 + qi] = val;
        }
    }
}

extern "C" void kernel_launch(void* const* d_in, const int* in_sizes, int n_in,
                              void* d_out, int out_size, void* d_ws, size_t ws_size,
                              hipStream_t stream)
{
    const float* fmap1  = (const float*)d_in[0];
    const float* fmap2  = (const float*)d_in[1];
    const float* coords = (const float*)d_in[2];
    float* out = (float*)d_out;

    char* ws = (char*)d_ws;
    const size_t A_BYTES   = (size_t)NB * NQ * ND * 2;      //  8.4 MB
    const size_t B_BYTES   = (size_t)NB * MPAD * ND * 2;    // 11.3 MB
    const size_t CMP_BYTES = (size_t)NB * NQ * 400 * 2;     // 13.1 MB
    const size_t TBL_BYTES = (size_t)NB * 4 * NQ * 4;       //  256 KB
    ushort_t* Abf  = (ushort_t*)ws;
    ushort_t* Ball = (ushort_t*)(ws + A_BYTES);
    ushort_t* cmp  = (ushort_t*)(ws + A_BYTES + B_BYTES);
    int*      tblS = (int*)(ws + A_BYTES + B_BYTES + CMP_BYTES);
    int*      perm = (int*)(ws + A_BYTES + B_BYTES + CMP_BYTES + TBL_BYTES);

    sort_kernel<<<NB, 256, 0, stream>>>(coords, perm);
    tbls_kernel<<<(NB * NQ) / 256, 256, 0, stream>>>(coords, perm, tblS);

    pre_kernel<<<dim3(64, 4, 8), 256, 0, stream>>>(fmap1, fmap2, Abf, Ball);

    pool_fused<<<NB * 64, 256, 0, stream>>>(Ball);

    gemm_corr<<<dim3(16 * 43 * NB), 512, 0, stream>>>(Abf, Ball, cmp, perm, tblS);

    sample_kernel<<<dim3(256, NLVL, NB), 256, 0, stream>>>(cmp, coords, out);
}